// Round 2
// baseline (1633.348 us; speedup 1.0000x reference)
//
#include <hip/hip_runtime.h>
#include <hip/hip_bf16.h>
#include <math.h>

#define DIMC 256
#define QSZ  56
#define NHEAD 8
#define HDIM 32
#define WSZ  7
#define SSZ  3
#define LWIN 49
#define NWIN 64
#define HW   3136          // 56*56
#define NTOK 50176         // 16*3136
#define FFWD 1024
#define CHUNK 6272         // NTOK/8

__device__ __forceinline__ int region_of(int h) {
    return (h < 49) ? 0 : ((h < 53) ? 1 : 2);
}

// map partitioned row m = ((b*64 + wi)*49 + p) -> flat token index b*3136 + h*56 + w
// (accounts for the cyclic shift by SSZ: rolled pos (hr,wr) <- source (hr+3)%56)
__device__ __forceinline__ int row2tok(int m) {
    int b  = m / (NWIN * LWIN);
    int r  = m - b * (NWIN * LWIN);
    int wi = r / LWIN;
    int p  = r - wi * LWIN;
    int wh = wi >> 3, ww = wi & 7;
    int ph = p / 7,   pw = p - ph * 7;
    int hr = wh * 7 + ph, wr = ww * 7 + pw;
    int hs = hr + SSZ; if (hs >= QSZ) hs -= QSZ;
    int ws2 = wr + SSZ; if (ws2 >= QSZ) ws2 -= QSZ;
    return b * HW + hs * QSZ + ws2;
}

// ---------------- K1: BCHW -> BHWC transpose + LN1 (writes hln only) ----------
__global__ __launch_bounds__(256) void k_ln1(const float* __restrict__ x,
        const float* __restrict__ g, const float* __restrict__ be,
        float* __restrict__ hln) {
    __shared__ float tile[32][257];
    __shared__ float msh[32], rsh[32];
    int blk = blockIdx.x;            // 16 * 98
    int b   = blk / 98;
    int hw0 = (blk - b * 98) * 32;
    int t   = threadIdx.x;
    int tx  = t & 31, ty = t >> 5;
    for (int c = ty; c < 256; c += 8)
        tile[tx][c] = x[(size_t)(b * 256 + c) * HW + hw0 + tx];
    __syncthreads();
    int row = t >> 3, sub = t & 7;
    float s = 0.f, sq = 0.f;
    for (int c = sub * 32; c < sub * 32 + 32; ++c) {
        float v = tile[row][c]; s += v; sq += v * v;
    }
    for (int o = 4; o; o >>= 1) { s += __shfl_down(s, o, 8); sq += __shfl_down(sq, o, 8); }
    if (sub == 0) {
        float m   = s * (1.f / 256.f);
        float var = sq * (1.f / 256.f) - m * m;
        msh[row] = m; rsh[row] = rsqrtf(var + 1e-5f);
    }
    __syncthreads();
    float gg = g[t], bb = be[t];      // t == channel
    for (int r2 = 0; r2 < 32; ++r2) {
        float v = tile[r2][t];
        hln[(size_t)(b * HW + hw0 + r2) * 256 + t] = (v - msh[r2]) * rsh[r2] * gg + bb;
    }
}

// ---------------- K4b: x1 += transpose(x)  (BCHW -> token-major add) ----------
__global__ __launch_bounds__(256) void k_addx(const float* __restrict__ x,
        float* __restrict__ x1) {
    __shared__ float tile[32][257];
    int blk = blockIdx.x;
    int b   = blk / 98;
    int hw0 = (blk - b * 98) * 32;
    int t   = threadIdx.x;
    int tx  = t & 31, ty = t >> 5;
    for (int c = ty; c < 256; c += 8)
        tile[tx][c] = x[(size_t)(b * 256 + c) * HW + hw0 + tx];
    __syncthreads();
    for (int r = 0; r < 32; ++r) {
        size_t o = (size_t)(b * HW + hw0 + r) * 256 + t;
        x1[o] += tile[r][t];
    }
}

// ---------------- generic 64x64x16 fp32 GEMM --------------------------------
// MODE 0: qkv   — gather A rows via row2tok, C(bf16) = acc + bias          (N=768)
// MODE 1: proj  — identity A, scatter rows via row2tok, C = acc + bias     (N=256)
// MODE 2: ffn1  — identity, C = relu(acc + bias), C rows local             (N=1024)
// MODE 3: ffn2  — A rows local, y = x1 + ls*(acc+bias), BCHW transposed    (N=256)
template<int MODE>
__global__ __launch_bounds__(256) void k_gemm(const float* __restrict__ A,
        const float* __restrict__ Bw, const float* __restrict__ bias,
        void* __restrict__ Cv, int K, int N,
        const float* __restrict__ extra, const float* __restrict__ extra2,
        int grow0) {
    __shared__ float As[16][68];
    __shared__ float Bs[16][64];
    int m0 = blockIdx.x * 64, n0 = blockIdx.y * 64;
    int t  = threadIdx.x;
    int lm  = t >> 2, lk4 = (t & 3) * 4;
    int arow = m0 + lm;
    int agrow = (MODE == 0) ? row2tok(arow) : arow;
    const float* Aptr = A + (size_t)agrow * K + lk4;
    int lkb = t >> 4, lnb = (t & 15) * 4;
    const float* Bptr = Bw + (size_t)lkb * N + n0 + lnb;
    int tm = (t & 15) * 4, tn = (t >> 4) * 4;
    float acc[4][4] = {};
    for (int k0 = 0; k0 < K; k0 += 16) {
        float4 av = *(const float4*)(Aptr + k0);
        float4 bv = *(const float4*)(Bptr + (size_t)k0 * N);
        __syncthreads();
        As[lk4 + 0][lm] = av.x;
        As[lk4 + 1][lm] = av.y;
        As[lk4 + 2][lm] = av.z;
        As[lk4 + 3][lm] = av.w;
        *(float4*)&Bs[lkb][lnb] = bv;
        __syncthreads();
#pragma unroll
        for (int k = 0; k < 16; ++k) {
            float4 a = *(const float4*)&As[k][tm];
            float4 b = *(const float4*)&Bs[k][tn];
            acc[0][0] += a.x * b.x; acc[0][1] += a.x * b.y; acc[0][2] += a.x * b.z; acc[0][3] += a.x * b.w;
            acc[1][0] += a.y * b.x; acc[1][1] += a.y * b.y; acc[1][2] += a.y * b.z; acc[1][3] += a.y * b.w;
            acc[2][0] += a.z * b.x; acc[2][1] += a.z * b.y; acc[2][2] += a.z * b.z; acc[2][3] += a.z * b.w;
            acc[3][0] += a.w * b.x; acc[3][1] += a.w * b.y; acc[3][2] += a.w * b.z; acc[3][3] += a.w * b.w;
        }
    }
    float4 bb = *(const float4*)(bias + n0 + tn);
    if constexpr (MODE == 0) {
        __hip_bfloat16* Cb = (__hip_bfloat16*)Cv;
#pragma unroll
        for (int i = 0; i < 4; ++i) {
            size_t base = (size_t)(m0 + tm + i) * N + n0 + tn;
            Cb[base + 0] = __float2bfloat16(acc[i][0] + bb.x);
            Cb[base + 1] = __float2bfloat16(acc[i][1] + bb.y);
            Cb[base + 2] = __float2bfloat16(acc[i][2] + bb.z);
            Cb[base + 3] = __float2bfloat16(acc[i][3] + bb.w);
        }
    } else if constexpr (MODE == 1) {
        float* C = (float*)Cv;
#pragma unroll
        for (int i = 0; i < 4; ++i) {
            int tok = row2tok(m0 + tm + i);
            size_t base = (size_t)tok * 256 + n0 + tn;
            float4 o{acc[i][0] + bb.x, acc[i][1] + bb.y, acc[i][2] + bb.z, acc[i][3] + bb.w};
            *(float4*)(C + base) = o;
        }
    } else if constexpr (MODE == 2) {
        float* C = (float*)Cv;
#pragma unroll
        for (int i = 0; i < 4; ++i) {
            float4 o{fmaxf(acc[i][0] + bb.x, 0.f), fmaxf(acc[i][1] + bb.y, 0.f),
                     fmaxf(acc[i][2] + bb.z, 0.f), fmaxf(acc[i][3] + bb.w, 0.f)};
            *(float4*)(C + (size_t)(m0 + tm + i) * N + n0 + tn) = o;
        }
    } else {
        float* C = (float*)Cv;
        __shared__ float Ts[64][65];
        float4 ls = *(const float4*)(extra2 + n0 + tn);
#pragma unroll
        for (int i = 0; i < 4; ++i) {
            int grow = grow0 + m0 + tm + i;
            float4 xv = *(const float4*)(extra + (size_t)grow * 256 + n0 + tn);
            Ts[tm + i][tn + 0] = xv.x + ls.x * (acc[i][0] + bb.x);
            Ts[tm + i][tn + 1] = xv.y + ls.y * (acc[i][1] + bb.y);
            Ts[tm + i][tn + 2] = xv.z + ls.z * (acc[i][2] + bb.z);
            Ts[tm + i][tn + 3] = xv.w + ls.w * (acc[i][3] + bb.w);
        }
        __syncthreads();
        int m0g = grow0 + m0;           // 3136 % 64 == 0: tile never crosses batch
        int bI  = m0g / HW;
        int hw0 = m0g - bI * HW;
        for (int idx = t; idx < 4096; idx += 256) {
            int n = idx >> 6, m = idx & 63;
            C[(size_t)(bI * 256 + n0 + n) * HW + hw0 + m] = Ts[m][n];
        }
    }
}

// ---------------- K3: windowed attention, one block per (window, head) --------
__global__ __launch_bounds__(256) void k_attn(const __hip_bfloat16* __restrict__ qkv,
        float* __restrict__ oattn) {
    __shared__ float Qs[49][33], Ks[49][33], Vs[49][33], Ss[49][50];
    int blk  = blockIdx.x;             // 1024 windows * 8 heads
    int head = blk & 7;
    int win  = blk >> 3;               // b*64 + wi
    int wi   = win & 63;
    int rowbase = win * LWIN;
    int t = threadIdx.x;
    const __hip_bfloat16* qb = qkv + (size_t)rowbase * 768 + head * 32;
    for (int idx = t; idx < LWIN * 32; idx += 256) {
        int p = idx >> 5, c = idx & 31;
        Qs[p][c] = __bfloat162float(qb[p * 768 + c]);
        Ks[p][c] = __bfloat162float(qb[p * 768 + 256 + c]);
        Vs[p][c] = __bfloat162float(qb[p * 768 + 512 + c]);
    }
    __syncthreads();
    int wh = wi >> 3, ww = wi & 7;
    for (int idx = t; idx < LWIN * LWIN; idx += 256) {
        int i = idx / 49, j = idx - i * 49;
        float s = 0.f;
#pragma unroll
        for (int c = 0; c < 32; ++c) s += Qs[i][c] * Ks[j][c];
        int ih = wh * 7 + i / 7, iw = ww * 7 + i % 7;
        int jh = wh * 7 + j / 7, jw = ww * 7 + j % 7;
        int idi = region_of(ih) * 3 + region_of(iw);
        int idj = region_of(jh) * 3 + region_of(jw);
        s = s * 0.17677669529663687f + ((idi != idj) ? -100.f : 0.f);
        Ss[i][j] = s;
    }
    __syncthreads();
    if (t < LWIN) {
        float mx = -1e30f;
        for (int j = 0; j < LWIN; ++j) mx = fmaxf(mx, Ss[t][j]);
        float sum = 0.f;
        for (int j = 0; j < LWIN; ++j) { float e = expf(Ss[t][j] - mx); Ss[t][j] = e; sum += e; }
        float inv = 1.f / sum;
        for (int j = 0; j < LWIN; ++j) Ss[t][j] *= inv;
    }
    __syncthreads();
    for (int idx = t; idx < LWIN * 32; idx += 256) {
        int p = idx >> 5, c = idx & 31;
        float s = 0.f;
        for (int j = 0; j < LWIN; ++j) s += Ss[p][j] * Vs[j][c];
        oattn[(size_t)(rowbase + p) * 256 + head * 32 + c] = s;
    }
}

// ---------------- K5: LN2, one wave per token ---------------------------------
__global__ __launch_bounds__(256) void k_ln2(const float* __restrict__ x1,
        const float* __restrict__ g, const float* __restrict__ be,
        float* __restrict__ h2) {
    int wave = threadIdx.x >> 6, lane = threadIdx.x & 63;
    int tok  = blockIdx.x * 4 + wave;
    const float* p = x1 + (size_t)tok * 256 + lane * 4;
    float4 v = *(const float4*)p;
    float s  = v.x + v.y + v.z + v.w;
    float sq = v.x * v.x + v.y * v.y + v.z * v.z + v.w * v.w;
    for (int o = 32; o; o >>= 1) { s += __shfl_xor(s, o); sq += __shfl_xor(sq, o); }
    float m  = s * (1.f / 256.f);
    float rs = rsqrtf(sq * (1.f / 256.f) - m * m + 1e-5f);
    float4 gv = *(const float4*)(g + lane * 4);
    float4 bv = *(const float4*)(be + lane * 4);
    float4 o4{(v.x - m) * rs * gv.x + bv.x, (v.y - m) * rs * gv.y + bv.y,
              (v.z - m) * rs * gv.z + bv.z, (v.w - m) * rs * gv.w + bv.w};
    *(float4*)(h2 + (size_t)tok * 256 + lane * 4) = o4;
}

extern "C" void kernel_launch(void* const* d_in, const int* in_sizes, int n_in,
                              void* d_out, int out_size, void* d_ws, size_t ws_size,
                              hipStream_t stream) {
    const float* x      = (const float*)d_in[0];
    const float* ln1_g  = (const float*)d_in[1];
    const float* ln1_b  = (const float*)d_in[2];
    const float* ln2_g  = (const float*)d_in[3];
    const float* ln2_b  = (const float*)d_in[4];
    const float* qkv_w  = (const float*)d_in[5];
    const float* qkv_b  = (const float*)d_in[6];
    const float* proj_w = (const float*)d_in[7];
    const float* proj_b = (const float*)d_in[8];
    const float* ffn_w1 = (const float*)d_in[9];
    const float* ffn_b1 = (const float*)d_in[10];
    const float* ffn_w2 = (const float*)d_in[11];
    const float* ffn_b2 = (const float*)d_in[12];
    const float* lscale = (const float*)d_in[13];

    // workspace layout (byte offsets), total 128,450,560 B (~122.5 MiB):
    //   A  @ 0          : 51,380,224 B  fp32  hln -> o_attn -> h2
    //   B  @ 51,380,224 : 77,070,336 B  phase1: qkv bf16 (50176x768)
    //                                    phase2: x1 fp32 (51,380,224 B)
    //                                          + f1 chunk fp32 @ +51,380,224 (25,690,112 B)
    char* wsb = (char*)d_ws;
    float* A   = (float*)wsb;
    __hip_bfloat16* qkvb = (__hip_bfloat16*)(wsb + 51380224);
    float* x1  = (float*)(wsb + 51380224);
    float* f1  = (float*)(wsb + 51380224 + 51380224);

    // K1: transpose + LN1 -> hln (A)
    k_ln1<<<16 * 98, 256, 0, stream>>>(x, ln1_g, ln1_b, A);
    // K2: QKV gemm (gathered A rows) -> qkv bf16
    k_gemm<0><<<dim3(784, 12), 256, 0, stream>>>(A, qkv_w, qkv_b, qkvb, 256, 768, nullptr, nullptr, 0);
    // K3: attention -> o_attn (A; hln dead)
    k_attn<<<8192, 256, 0, stream>>>(qkvb, A);
    // K4: proj gemm + reverse-partition scatter -> x1 (overwrites dead qkv)
    k_gemm<1><<<dim3(784, 4), 256, 0, stream>>>(A, proj_w, proj_b, x1, 256, 256, nullptr, nullptr, 0);
    // K4b: x1 += transpose(x)
    k_addx<<<16 * 98, 256, 0, stream>>>(x, x1);
    // K5: LN2 -> h2 (A; o_attn dead)
    k_ln2<<<12544, 256, 0, stream>>>(x1, ln2_g, ln2_b, A);
    // K6/K7: FFN in 8 token-chunks of 6272 rows
    for (int c = 0; c < 8; ++c) {
        k_gemm<2><<<dim3(98, 16), 256, 0, stream>>>(A + (size_t)c * CHUNK * 256, ffn_w1, ffn_b1,
                                                    f1, 256, 1024, nullptr, nullptr, 0);
        k_gemm<3><<<dim3(98, 4), 256, 0, stream>>>(f1, ffn_w2, ffn_b2, (float*)d_out, 1024, 256,
                                                   x1, lscale, c * CHUNK);
    }
}

// Round 3
// 487.456 us; speedup vs baseline: 3.3508x; 3.3508x over previous
//
#include <hip/hip_runtime.h>
#include <hip/hip_bf16.h>
#include <math.h>

typedef unsigned short u16;
typedef __bf16 bf16x8 __attribute__((ext_vector_type(8)));
typedef float  f32x4  __attribute__((ext_vector_type(4)));

#define DIMC 256
#define QSZ  56
#define WSZ  7
#define SSZ  3
#define LWIN 49
#define NWIN 64
#define HW   3136          // 56*56
#define NTOK 50176         // 16*3136
#define FFWD 1024
#define FCH  12544         // NTOK/4 ffn chunk rows

__device__ __forceinline__ u16 f2bu(float f) {
    __hip_bfloat16 h = __float2bfloat16(f);
    return __builtin_bit_cast(u16, h);
}
__device__ __forceinline__ float bu2f(u16 u) {
    unsigned v = (unsigned)u << 16;
    return __builtin_bit_cast(float, v);
}
__device__ __forceinline__ void gload_lds16(const void* g, void* l) {
    __builtin_amdgcn_global_load_lds((const __attribute__((address_space(1))) void*)g,
                                     (__attribute__((address_space(3))) void*)l, 16, 0, 0);
}

__device__ __forceinline__ int region_of(int h) {
    return (h < 49) ? 0 : ((h < 53) ? 1 : 2);
}

// partitioned row m = ((b*64 + wi)*49 + p) -> flat token index (with roll by -3)
__device__ __forceinline__ int row2tok(int m) {
    int b  = m / (NWIN * LWIN);
    int r  = m - b * (NWIN * LWIN);
    int wi = r / LWIN;
    int p  = r - wi * LWIN;
    int wh = wi >> 3, ww = wi & 7;
    int ph = p / 7,   pw = p - ph * 7;
    int hr = wh * 7 + ph, wr = ww * 7 + pw;
    int hs = hr + SSZ; if (hs >= QSZ) hs -= QSZ;
    int ws2 = wr + SSZ; if (ws2 >= QSZ) ws2 -= QSZ;
    return b * HW + hs * QSZ + ws2;
}

// ---------------- weight transpose + bf16 convert: Wt[n][k] = bf16(W[k][n]) ---
__global__ __launch_bounds__(256) void k_wconv(const float* __restrict__ W,
        u16* __restrict__ Wt, int K, int N) {
    __shared__ float tile[32][33];
    int k0 = blockIdx.x * 32, n0 = blockIdx.y * 32;
    int tx = threadIdx.x & 31, ty = threadIdx.x >> 5;
    for (int kk = ty; kk < 32; kk += 8)
        tile[kk][tx] = W[(size_t)(k0 + kk) * N + n0 + tx];
    __syncthreads();
    for (int nn = ty; nn < 32; nn += 8)
        Wt[(size_t)(n0 + nn) * K + k0 + tx] = f2bu(tile[tx][nn]);
}

// ---------------- K1: BCHW -> token-major transpose + LN1 -> bf16 -------------
__global__ __launch_bounds__(256) void k_ln1(const float* __restrict__ x,
        const float* __restrict__ g, const float* __restrict__ be,
        u16* __restrict__ hln) {
    __shared__ float tile[32][257];
    __shared__ float msh[32], rsh[32];
    int blk = blockIdx.x;            // 16 * 98
    int b   = blk / 98;
    int hw0 = (blk - b * 98) * 32;
    int t   = threadIdx.x;
    int tx  = t & 31, ty = t >> 5;
    for (int c = ty; c < 256; c += 8)
        tile[tx][c] = x[(size_t)(b * 256 + c) * HW + hw0 + tx];
    __syncthreads();
    int row = t >> 3, sub = t & 7;
    float s = 0.f, sq = 0.f;
    for (int c = sub * 32; c < sub * 32 + 32; ++c) {
        float v = tile[row][c]; s += v; sq += v * v;
    }
    for (int o = 4; o; o >>= 1) { s += __shfl_down(s, o, 8); sq += __shfl_down(sq, o, 8); }
    if (sub == 0) {
        float m   = s * (1.f / 256.f);
        float var = sq * (1.f / 256.f) - m * m;
        msh[row] = m; rsh[row] = rsqrtf(var + 1e-5f);
    }
    __syncthreads();
    float gg = g[t], bb = be[t];
    for (int r2 = 0; r2 < 32; ++r2) {
        float v = tile[r2][t];
        hln[(size_t)(b * HW + hw0 + r2) * 256 + t] = f2bu((v - msh[r2]) * rsh[r2] * gg + bb);
    }
}

// ---------------- x1 += transpose(x) ------------------------------------------
__global__ __launch_bounds__(256) void k_addx(const float* __restrict__ x,
        float* __restrict__ x1) {
    __shared__ float tile[32][257];
    int blk = blockIdx.x;
    int b   = blk / 98;
    int hw0 = (blk - b * 98) * 32;
    int t   = threadIdx.x;
    int tx  = t & 31, ty = t >> 5;
    for (int c = ty; c < 256; c += 8)
        tile[tx][c] = x[(size_t)(b * 256 + c) * HW + hw0 + tx];
    __syncthreads();
    for (int r = 0; r < 32; ++r) {
        size_t o = (size_t)(b * HW + hw0 + r) * 256 + t;
        x1[o] += tile[r][t];
    }
}

// ---------------- MFMA bf16 GEMM, 128x128 tile, BK=32, 4 waves ----------------
// A [M][K] bf16 (MODE 0: rows gathered via row2tok), Bt [N][K] bf16.
// MODE 0: qkv  -> bf16 C = acc + bias                       (N=768)
// MODE 1: proj -> fp32 x1 scattered rows (row2tok), + bias  (N=256)
// MODE 2: ffn1 -> bf16 relu(acc + bias)                     (N=1024)
// MODE 3: ffn2 -> fp32 BCHW d_out = x1 + ls*(acc+bias)      (N=256)
template<int MODE>
__global__ __launch_bounds__(256) void k_mgemm(
        const u16* __restrict__ A, const u16* __restrict__ Bt,
        const float* __restrict__ bias, void* __restrict__ Cv,
        int K, int N, const float* __restrict__ extra,
        const float* __restrict__ extra2, int grow0) {
    __shared__ __align__(16) u16 As[128 * 32];
    __shared__ __align__(16) u16 Bs[128 * 32];
    const int m0 = blockIdx.x * 128, n0 = blockIdx.y * 128;
    const int t = threadIdx.x, lane = t & 63;
    const int wv = t >> 6, wr = wv >> 1, wc = wv & 1;

    int ar0 = m0 + (t >> 2), ar1 = ar0 + 64;
    if (MODE == 0) { ar0 = row2tok(ar0); ar1 = row2tok(ar1); }
    const u16* gA0 = A  + (size_t)ar0 * K + (t & 3) * 8;
    const u16* gA1 = A  + (size_t)ar1 * K + (t & 3) * 8;
    const u16* gB0 = Bt + (size_t)(n0 + (t >> 2)) * K + (t & 3) * 8;
    const u16* gB1 = Bt + (size_t)(n0 + 64 + (t >> 2)) * K + (t & 3) * 8;
    u16* lA0 = As + t * 8;  u16* lA1 = As + 2048 + t * 8;
    u16* lB0 = Bs + t * 8;  u16* lB1 = Bs + 2048 + t * 8;

    f32x4 acc[4][4] = {};
    const int ra = wr * 64 + (lane & 15);
    const int rb = wc * 64 + (lane & 15);
    const int ko = (lane >> 4) * 8;

    for (int k0 = 0; k0 < K; k0 += 32) {
        __syncthreads();
        gload_lds16(gA0 + k0, lA0);
        gload_lds16(gA1 + k0, lA1);
        gload_lds16(gB0 + k0, lB0);
        gload_lds16(gB1 + k0, lB1);
        __syncthreads();
        bf16x8 af[4], bfr[4];
#pragma unroll
        for (int i = 0; i < 4; ++i)
            af[i] = *(const bf16x8*)(As + (ra + i * 16) * 32 + ko);
#pragma unroll
        for (int j = 0; j < 4; ++j)
            bfr[j] = *(const bf16x8*)(Bs + (rb + j * 16) * 32 + ko);
#pragma unroll
        for (int i = 0; i < 4; ++i)
#pragma unroll
            for (int j = 0; j < 4; ++j)
                acc[i][j] = __builtin_amdgcn_mfma_f32_16x16x32_bf16(af[i], bfr[j], acc[i][j], 0, 0, 0);
    }

    const int colb = n0 + wc * 64 + (lane & 15);       // + j*16
    const int rowb = m0 + wr * 64 + ((lane >> 4) * 4); // + i*16 + r

    if constexpr (MODE == 0) {
        u16* Cb = (u16*)Cv;
#pragma unroll
        for (int j = 0; j < 4; ++j) {
            int col = colb + j * 16; float bj = bias[col];
#pragma unroll
            for (int i = 0; i < 4; ++i) {
                int rw = rowb + i * 16;
#pragma unroll
                for (int r = 0; r < 4; ++r)
                    Cb[(size_t)(rw + r) * N + col] = f2bu(acc[i][j][r] + bj);
            }
        }
    } else if constexpr (MODE == 1) {
        float* C = (float*)Cv;
        int tok[4][4];
#pragma unroll
        for (int i = 0; i < 4; ++i)
#pragma unroll
            for (int r = 0; r < 4; ++r)
                tok[i][r] = row2tok(rowb + i * 16 + r);
#pragma unroll
        for (int j = 0; j < 4; ++j) {
            int col = colb + j * 16; float bj = bias[col];
#pragma unroll
            for (int i = 0; i < 4; ++i)
#pragma unroll
                for (int r = 0; r < 4; ++r)
                    C[(size_t)tok[i][r] * 256 + col] = acc[i][j][r] + bj;
        }
    } else if constexpr (MODE == 2) {
        u16* Cb = (u16*)Cv;
#pragma unroll
        for (int j = 0; j < 4; ++j) {
            int col = colb + j * 16; float bj = bias[col];
#pragma unroll
            for (int i = 0; i < 4; ++i) {
                int rw = rowb + i * 16;
#pragma unroll
                for (int r = 0; r < 4; ++r)
                    Cb[(size_t)(rw + r) * N + col] = f2bu(fmaxf(acc[i][j][r] + bj, 0.f));
            }
        }
    } else {
        float* C = (float*)Cv;
#pragma unroll
        for (int j = 0; j < 4; ++j) {
            int col = colb + j * 16;
            float bj = bias[col], lj = extra2[col];
#pragma unroll
            for (int i = 0; i < 4; ++i) {
                int g  = grow0 + rowb + i * 16;
                int b  = g / HW, hw = g - b * HW;
                f32x4 o;
#pragma unroll
                for (int r = 0; r < 4; ++r)
                    o[r] = extra[(size_t)(g + r) * 256 + col] + lj * (acc[i][j][r] + bj);
                *(f32x4*)(C + ((size_t)(b * 256 + col)) * HW + hw) = o;
            }
        }
    }
}

// ---------------- attention: one block per (window, head), fp32 in LDS --------
__global__ __launch_bounds__(256) void k_attn(const u16* __restrict__ qkv,
        u16* __restrict__ oattn) {
    __shared__ float Qs[49][33], Ks[49][33], Vs[49][33], Ss[49][50];
    int blk  = blockIdx.x;             // 1024 windows * 8 heads
    int head = blk & 7;
    int win  = blk >> 3;
    int wi   = win & 63;
    int rowbase = win * LWIN;
    int t = threadIdx.x;
    const u16* qb = qkv + (size_t)rowbase * 768 + head * 32;
    for (int idx = t; idx < LWIN * 32; idx += 256) {
        int p = idx >> 5, c = idx & 31;
        Qs[p][c] = bu2f(qb[p * 768 + c]);
        Ks[p][c] = bu2f(qb[p * 768 + 256 + c]);
        Vs[p][c] = bu2f(qb[p * 768 + 512 + c]);
    }
    __syncthreads();
    int wh = wi >> 3, ww = wi & 7;
    for (int idx = t; idx < LWIN * LWIN; idx += 256) {
        int i = idx / 49, j = idx - i * 49;
        float s = 0.f;
#pragma unroll
        for (int c = 0; c < 32; ++c) s += Qs[i][c] * Ks[j][c];
        int ih = wh * 7 + i / 7, iw = ww * 7 + i % 7;
        int jh = wh * 7 + j / 7, jw = ww * 7 + j % 7;
        int idi = region_of(ih) * 3 + region_of(iw);
        int idj = region_of(jh) * 3 + region_of(jw);
        s = s * 0.17677669529663687f + ((idi != idj) ? -100.f : 0.f);
        Ss[i][j] = s;
    }
    __syncthreads();
    if (t < LWIN) {
        float mx = -1e30f;
        for (int j = 0; j < LWIN; ++j) mx = fmaxf(mx, Ss[t][j]);
        float sum = 0.f;
        for (int j = 0; j < LWIN; ++j) { float e = expf(Ss[t][j] - mx); Ss[t][j] = e; sum += e; }
        float inv = 1.f / sum;
        for (int j = 0; j < LWIN; ++j) Ss[t][j] *= inv;
    }
    __syncthreads();
    for (int idx = t; idx < LWIN * 32; idx += 256) {
        int p = idx >> 5, c = idx & 31;
        float s = 0.f;
        for (int j = 0; j < LWIN; ++j) s += Ss[p][j] * Vs[j][c];
        oattn[(size_t)(rowbase + p) * 256 + head * 32 + c] = f2bu(s);
    }
}

// ---------------- LN2 -> bf16, one wave per token -----------------------------
__global__ __launch_bounds__(256) void k_ln2(const float* __restrict__ x1,
        const float* __restrict__ g, const float* __restrict__ be,
        u16* __restrict__ h2) {
    int wave = threadIdx.x >> 6, lane = threadIdx.x & 63;
    int tok  = blockIdx.x * 4 + wave;
    const float* p = x1 + (size_t)tok * 256 + lane * 4;
    float4 v = *(const float4*)p;
    float s  = v.x + v.y + v.z + v.w;
    float sq = v.x * v.x + v.y * v.y + v.z * v.z + v.w * v.w;
    for (int o = 32; o; o >>= 1) { s += __shfl_xor(s, o); sq += __shfl_xor(sq, o); }
    float m  = s * (1.f / 256.f);
    float rs = rsqrtf(sq * (1.f / 256.f) - m * m + 1e-5f);
    float4 gv = *(const float4*)(g + lane * 4);
    float4 bv = *(const float4*)(be + lane * 4);
    unsigned p0 = (unsigned)f2bu((v.x - m) * rs * gv.x + bv.x)
                | ((unsigned)f2bu((v.y - m) * rs * gv.y + bv.y) << 16);
    unsigned p1 = (unsigned)f2bu((v.z - m) * rs * gv.z + bv.z)
                | ((unsigned)f2bu((v.w - m) * rs * gv.w + bv.w) << 16);
    unsigned* dst = (unsigned*)(h2 + (size_t)tok * 256 + lane * 4);
    dst[0] = p0; dst[1] = p1;
}

extern "C" void kernel_launch(void* const* d_in, const int* in_sizes, int n_in,
                              void* d_out, int out_size, void* d_ws, size_t ws_size,
                              hipStream_t stream) {
    const float* x      = (const float*)d_in[0];
    const float* ln1_g  = (const float*)d_in[1];
    const float* ln1_b  = (const float*)d_in[2];
    const float* ln2_g  = (const float*)d_in[3];
    const float* ln2_b  = (const float*)d_in[4];
    const float* qkv_w  = (const float*)d_in[5];
    const float* qkv_b  = (const float*)d_in[6];
    const float* proj_w = (const float*)d_in[7];
    const float* proj_b = (const float*)d_in[8];
    const float* ffn_w1 = (const float*)d_in[9];
    const float* ffn_b1 = (const float*)d_in[10];
    const float* ffn_w2 = (const float*)d_in[11];
    const float* ffn_b2 = (const float*)d_in[12];
    const float* lscale = (const float*)d_in[13];

    // workspace: total 104,333,312 B
    //   0        : wqt 768x256 bf16   (393,216)
    //   393216   : wpt 256x256 bf16   (131,072)
    //   524288   : w1t 1024x256 bf16  (524,288)
    //   1048576  : w2t 256x1024 bf16  (524,288)
    //   1572864  : P  25,690,112 B    hln -> o_attn -> h2 (bf16 50176x256)
    //   27262976 : Q  77,070,336 B    qkv bf16 (50176x768)
    //                                  then x1 fp32 (51,380,224) + f1c bf16 (25,690,112)
    char* wsb = (char*)d_ws;
    u16* wqt  = (u16*)(wsb);
    u16* wpt  = (u16*)(wsb + 393216);
    u16* w1t  = (u16*)(wsb + 524288);
    u16* w2t  = (u16*)(wsb + 1048576);
    u16* P    = (u16*)(wsb + 1572864);
    char* Qb  = wsb + 27262976;
    u16* qkvb = (u16*)Qb;
    float* x1 = (float*)Qb;
    u16* f1c  = (u16*)(Qb + 51380224);

    k_wconv<<<dim3(8, 24), 256, 0, stream>>>(qkv_w, wqt, 256, 768);
    k_wconv<<<dim3(8, 8),  256, 0, stream>>>(proj_w, wpt, 256, 256);
    k_wconv<<<dim3(8, 32), 256, 0, stream>>>(ffn_w1, w1t, 256, 1024);
    k_wconv<<<dim3(32, 8), 256, 0, stream>>>(ffn_w2, w2t, 1024, 256);

    k_ln1<<<16 * 98, 256, 0, stream>>>(x, ln1_g, ln1_b, P);
    k_mgemm<0><<<dim3(392, 6), 256, 0, stream>>>(P, wqt, qkv_b, qkvb, 256, 768,
                                                 nullptr, nullptr, 0);
    k_attn<<<8192, 256, 0, stream>>>(qkvb, P);
    k_mgemm<1><<<dim3(392, 2), 256, 0, stream>>>(P, wpt, proj_b, x1, 256, 256,
                                                 nullptr, nullptr, 0);
    k_addx<<<16 * 98, 256, 0, stream>>>(x, x1);
    k_ln2<<<12544, 256, 0, stream>>>(x1, ln2_g, ln2_b, P);
    for (int c = 0; c < 4; ++c) {
        k_mgemm<2><<<dim3(98, 8), 256, 0, stream>>>(P + (size_t)c * FCH * 256, w1t, ffn_b1,
                                                    f1c, 256, 1024, nullptr, nullptr, 0);
        k_mgemm<3><<<dim3(98, 2), 256, 0, stream>>>(f1c, w2t, ffn_b2, d_out, 1024, 256,
                                                    x1, lscale, c * FCH);
    }
}

// Round 5
// 408.437 us; speedup vs baseline: 3.9990x; 1.1935x over previous
//
#include <hip/hip_runtime.h>
#include <hip/hip_bf16.h>
#include <math.h>

typedef unsigned short u16;
typedef __bf16 bf16x8 __attribute__((ext_vector_type(8)));
typedef float  f32x4  __attribute__((ext_vector_type(4)));

#define DIMC 256
#define QSZ  56
#define WSZ  7
#define SSZ  3
#define LWIN 49
#define NWIN 64
#define HW   3136          // 56*56
#define NTOK 50176         // 16*3136
#define FFWD 1024
#define FCH  12544         // NTOK/4 ffn chunk rows

__device__ __forceinline__ u16 f2bu(float f) {
    __hip_bfloat16 h = __float2bfloat16(f);
    return __builtin_bit_cast(u16, h);
}
__device__ __forceinline__ float bu2f(u16 u) {
    unsigned v = (unsigned)u << 16;
    return __builtin_bit_cast(float, v);
}
__device__ __forceinline__ void gload_lds16(const void* g, void* l) {
    __builtin_amdgcn_global_load_lds((const __attribute__((address_space(1))) void*)g,
                                     (__attribute__((address_space(3))) void*)l, 16, 0, 0);
}

__device__ __forceinline__ int region_of(int h) {
    return (h < 49) ? 0 : ((h < 53) ? 1 : 2);
}

// partitioned row m = ((b*64 + wi)*49 + p) -> flat token index (with roll by -3)
__device__ __forceinline__ int row2tok(int m) {
    int b  = m / (NWIN * LWIN);
    int r  = m - b * (NWIN * LWIN);
    int wi = r / LWIN;
    int p  = r - wi * LWIN;
    int wh = wi >> 3, ww = wi & 7;
    int ph = p / 7,   pw = p - ph * 7;
    int hr = wh * 7 + ph, wr = ww * 7 + pw;
    int hs = hr + SSZ; if (hs >= QSZ) hs -= QSZ;
    int ws2 = wr + SSZ; if (ws2 >= QSZ) ws2 -= QSZ;
    return b * HW + hs * QSZ + ws2;
}

// ---------------- weight transpose + bf16 convert: Wt[n][k] = bf16(W[k][n]) ---
__global__ __launch_bounds__(256) void k_wconv(const float* __restrict__ W,
        u16* __restrict__ Wt, int K, int N) {
    __shared__ float tile[32][33];
    int k0 = blockIdx.x * 32, n0 = blockIdx.y * 32;
    int tx = threadIdx.x & 31, ty = threadIdx.x >> 5;
    for (int kk = ty; kk < 32; kk += 8)
        tile[kk][tx] = W[(size_t)(k0 + kk) * N + n0 + tx];
    __syncthreads();
    for (int nn = ty; nn < 32; nn += 8)
        Wt[(size_t)(n0 + nn) * K + k0 + tx] = f2bu(tile[tx][nn]);
}

// ---------------- K1: BCHW -> token-major transpose + LN1 -> bf16 -------------
__global__ __launch_bounds__(256) void k_ln1(const float* __restrict__ x,
        const float* __restrict__ g, const float* __restrict__ be,
        u16* __restrict__ hln) {
    __shared__ float tile[32][257];
    __shared__ float msh[32], rsh[32];
    int blk = blockIdx.x;            // 16 * 98
    int b   = blk / 98;
    int hw0 = (blk - b * 98) * 32;
    int t   = threadIdx.x;
    int tx  = t & 31, ty = t >> 5;
    for (int c = ty; c < 256; c += 8)
        tile[tx][c] = x[(size_t)(b * 256 + c) * HW + hw0 + tx];
    __syncthreads();
    int row = t >> 3, sub = t & 7;
    float s = 0.f, sq = 0.f;
    for (int c = sub * 32; c < sub * 32 + 32; ++c) {
        float v = tile[row][c]; s += v; sq += v * v;
    }
    for (int o = 4; o; o >>= 1) { s += __shfl_down(s, o, 8); sq += __shfl_down(sq, o, 8); }
    if (sub == 0) {
        float m   = s * (1.f / 256.f);
        float var = sq * (1.f / 256.f) - m * m;
        msh[row] = m; rsh[row] = rsqrtf(var + 1e-5f);
    }
    __syncthreads();
    float gg = g[t], bb = be[t];
    for (int r2 = 0; r2 < 32; ++r2) {
        float v = tile[r2][t];
        hln[(size_t)(b * HW + hw0 + r2) * 256 + t] = f2bu((v - msh[r2]) * rsh[r2] * gg + bb);
    }
}

// ---------------- x1 += transpose(x) ------------------------------------------
__global__ __launch_bounds__(256) void k_addx(const float* __restrict__ x,
        float* __restrict__ x1) {
    __shared__ float tile[32][257];
    int blk = blockIdx.x;
    int b   = blk / 98;
    int hw0 = (blk - b * 98) * 32;
    int t   = threadIdx.x;
    int tx  = t & 31, ty = t >> 5;
    for (int c = ty; c < 256; c += 8)
        tile[tx][c] = x[(size_t)(b * 256 + c) * HW + hw0 + tx];
    __syncthreads();
    for (int r = 0; r < 32; ++r) {
        size_t o = (size_t)(b * HW + hw0 + r) * 256 + t;
        x1[o] += tile[r][t];
    }
}

// ---------------- MFMA bf16 GEMM, 128x128 tile, BK=32, 4 waves ----------------
// A [M][K] bf16 (MODE 0: rows gathered via row2tok), Bt [N][K] bf16.
// MODE 0: qkv  -> bf16 C = acc + bias                       (N=768)
// MODE 1: proj -> fp32 x1 scattered rows (row2tok), + bias  (N=256)
// MODE 2: ffn1 -> bf16 relu(acc + bias)                     (N=1024)
// MODE 3: ffn2 -> fp32 BCHW d_out = x1 + ls*(acc+bias)      (N=256)
template<int MODE>
__global__ __launch_bounds__(256) void k_mgemm(
        const u16* __restrict__ A, const u16* __restrict__ Bt,
        const float* __restrict__ bias, void* __restrict__ Cv,
        int K, int N, const float* __restrict__ extra,
        const float* __restrict__ extra2, int grow0) {
    __shared__ __align__(16) u16 As[128 * 32];
    __shared__ __align__(16) u16 Bs[128 * 32];
    const int m0 = blockIdx.x * 128, n0 = blockIdx.y * 128;
    const int t = threadIdx.x, lane = t & 63;
    const int wv = t >> 6, wr = wv >> 1, wc = wv & 1;

    int ar0 = m0 + (t >> 2), ar1 = ar0 + 64;
    if (MODE == 0) { ar0 = row2tok(ar0); ar1 = row2tok(ar1); }
    const u16* gA0 = A  + (size_t)ar0 * K + (t & 3) * 8;
    const u16* gA1 = A  + (size_t)ar1 * K + (t & 3) * 8;
    const u16* gB0 = Bt + (size_t)(n0 + (t >> 2)) * K + (t & 3) * 8;
    const u16* gB1 = Bt + (size_t)(n0 + 64 + (t >> 2)) * K + (t & 3) * 8;
    u16* lA0 = As + t * 8;  u16* lA1 = As + 2048 + t * 8;
    u16* lB0 = Bs + t * 8;  u16* lB1 = Bs + 2048 + t * 8;

    f32x4 acc[4][4] = {};
    const int ra = wr * 64 + (lane & 15);
    const int rb = wc * 64 + (lane & 15);
    const int ko = (lane >> 4) * 8;

    for (int k0 = 0; k0 < K; k0 += 32) {
        __syncthreads();
        gload_lds16(gA0 + k0, lA0);
        gload_lds16(gA1 + k0, lA1);
        gload_lds16(gB0 + k0, lB0);
        gload_lds16(gB1 + k0, lB1);
        __syncthreads();
        bf16x8 af[4], bfr[4];
#pragma unroll
        for (int i = 0; i < 4; ++i)
            af[i] = *(const bf16x8*)(As + (ra + i * 16) * 32 + ko);
#pragma unroll
        for (int j = 0; j < 4; ++j)
            bfr[j] = *(const bf16x8*)(Bs + (rb + j * 16) * 32 + ko);
#pragma unroll
        for (int i = 0; i < 4; ++i)
#pragma unroll
            for (int j = 0; j < 4; ++j)
                acc[i][j] = __builtin_amdgcn_mfma_f32_16x16x32_bf16(af[i], bfr[j], acc[i][j], 0, 0, 0);
    }

    const int colb = n0 + wc * 64 + (lane & 15);       // + j*16
    const int rowb = m0 + wr * 64 + ((lane >> 4) * 4); // + i*16 + r

    if constexpr (MODE == 0) {
        u16* Cb = (u16*)Cv;
#pragma unroll
        for (int j = 0; j < 4; ++j) {
            int col = colb + j * 16; float bj = bias[col];
#pragma unroll
            for (int i = 0; i < 4; ++i) {
                int rw = rowb + i * 16;
#pragma unroll
                for (int r = 0; r < 4; ++r)
                    Cb[(size_t)(rw + r) * N + col] = f2bu(acc[i][j][r] + bj);
            }
        }
    } else if constexpr (MODE == 1) {
        float* C = (float*)Cv;
        int tok[4][4];
#pragma unroll
        for (int i = 0; i < 4; ++i)
#pragma unroll
            for (int r = 0; r < 4; ++r)
                tok[i][r] = row2tok(rowb + i * 16 + r);
#pragma unroll
        for (int j = 0; j < 4; ++j) {
            int col = colb + j * 16; float bj = bias[col];
#pragma unroll
            for (int i = 0; i < 4; ++i)
#pragma unroll
                for (int r = 0; r < 4; ++r)
                    C[(size_t)tok[i][r] * 256 + col] = acc[i][j][r] + bj;
        }
    } else if constexpr (MODE == 2) {
        u16* Cb = (u16*)Cv;
#pragma unroll
        for (int j = 0; j < 4; ++j) {
            int col = colb + j * 16; float bj = bias[col];
#pragma unroll
            for (int i = 0; i < 4; ++i) {
                int rw = rowb + i * 16;
#pragma unroll
                for (int r = 0; r < 4; ++r)
                    Cb[(size_t)(rw + r) * N + col] = f2bu(fmaxf(acc[i][j][r] + bj, 0.f));
            }
        }
    } else {
        float* C = (float*)Cv;
#pragma unroll
        for (int j = 0; j < 4; ++j) {
            int col = colb + j * 16;
            float bj = bias[col], lj = extra2[col];
#pragma unroll
            for (int i = 0; i < 4; ++i) {
                int g  = grow0 + rowb + i * 16;
                int b  = g / HW, hw = g - b * HW;
                f32x4 o;
#pragma unroll
                for (int r = 0; r < 4; ++r)
                    o[r] = extra[(size_t)(g + r) * 256 + col] + lj * (acc[i][j][r] + bj);
                *(f32x4*)(C + ((size_t)(b * 256 + col)) * HW + hw) = o;
            }
        }
    }
}

// ---------------- MFMA attention: one wave per (window, head) -----------------
// S = Q K^T (padded 64x64, K=32, 16 mfma), in-register masked softmax,
// P -> LDS (stride 72: 16B-aligned, 2-way bank alias = free), V staged
// transposed with rows 49..63 ZEROED (P tail cols are 0; 0*garbage in MFMA
// can be 0*Inf = NaN, so the K-pad tail must be explicitly zero).
__global__ __launch_bounds__(256) void k_attn(const u16* __restrict__ qkv,
        u16* __restrict__ oattn) {
    __shared__ __align__(16) u16 Pl[4][64 * 72];
    __shared__ __align__(16) u16 Vt[4][32 * 72];
    const int wv = threadIdx.x >> 6, lane = threadIdx.x & 63;
    const int task = blockIdx.x * 4 + wv;    // 8192 = 1024 win * 8 heads
    const int head = task & 7, win = task >> 3, wi = win & 63;
    const int rowbase = win * LWIN;
    const int g = lane >> 4, c = lane & 15, ko = g * 8;
    const u16* qb = qkv + (size_t)rowbase * 768 + head * 32;

    // --- S = Q K^T ---
    bf16x8 qf[4], kf[4];
#pragma unroll
    for (int i = 0; i < 4; ++i) {
        int r0 = i * 16 + c; if (r0 > 48) r0 = 48;   // clamp: garbage rows unused
        qf[i] = *(const bf16x8*)(qb + (size_t)r0 * 768 + ko);
        kf[i] = *(const bf16x8*)(qb + (size_t)r0 * 768 + 256 + ko);
    }
    f32x4 s[4][4] = {};
#pragma unroll
    for (int i = 0; i < 4; ++i)
#pragma unroll
        for (int j = 0; j < 4; ++j)
            s[i][j] = __builtin_amdgcn_mfma_f32_16x16x32_bf16(qf[i], kf[j], s[i][j], 0, 0, 0);

    // --- stage V transposed, zero-fill the K-pad rows 49..63 ---
    for (int idx = lane; idx < 64 * 32; idx += 64) {
        int vr = idx >> 5, vc = idx & 31;
        Vt[wv][vc * 72 + vr] = (vr < LWIN) ? qb[(size_t)vr * 768 + 512 + vc] : (u16)0;
    }

    // --- masked softmax in C-layout (row = i*16+g*4+r, col = j*16+c) ---
    const int wh7 = (wi >> 3) * 7, ww7 = (wi & 7) * 7;
    int idj[4]; bool jok[4];
#pragma unroll
    for (int j = 0; j < 4; ++j) {
        int col = j * 16 + c;
        jok[j] = col < LWIN;
        int p = jok[j] ? col : 48;
        idj[j] = region_of(wh7 + p / 7) * 3 + region_of(ww7 + p % 7);
    }
#pragma unroll
    for (int i = 0; i < 4; ++i) {
#pragma unroll
        for (int r = 0; r < 4; ++r) {
            int row = i * 16 + g * 4 + r;
            int p = row < LWIN ? row : 48;
            int idi = region_of(wh7 + p / 7) * 3 + region_of(ww7 + p % 7);
            float mx = -1e30f;
#pragma unroll
            for (int j = 0; j < 4; ++j) {
                float t = jok[j] ? fmaf(s[i][j][r], 0.17677669529663687f,
                                        (idi == idj[j]) ? 0.f : -100.f)
                                 : -1e30f;
                s[i][j][r] = t;
                mx = fmaxf(mx, t);
            }
            for (int o = 8; o; o >>= 1) mx = fmaxf(mx, __shfl_xor(mx, o));
            float ps = 0.f;
#pragma unroll
            for (int j = 0; j < 4; ++j) {
                float e = __expf(s[i][j][r] - mx);
                s[i][j][r] = e; ps += e;
            }
            for (int o = 8; o; o >>= 1) ps += __shfl_xor(ps, o);
            float inv = 1.f / ps;
#pragma unroll
            for (int j = 0; j < 4; ++j)
                Pl[wv][row * 72 + j * 16 + c] = f2bu(s[i][j][r] * inv);
        }
    }
    __syncthreads();

    // --- O = P V (M=64, N=32, K=64) ---
    bf16x8 vb[2][2];
#pragma unroll
    for (int j2 = 0; j2 < 2; ++j2) {
        vb[j2][0] = *(const bf16x8*)(&Vt[wv][(j2 * 16 + c) * 72 + ko]);
        vb[j2][1] = *(const bf16x8*)(&Vt[wv][(j2 * 16 + c) * 72 + ko + 32]);
    }
    f32x4 o[4][2] = {};
#pragma unroll
    for (int i = 0; i < 4; ++i) {
        bf16x8 pa0 = *(const bf16x8*)(&Pl[wv][(i * 16 + c) * 72 + ko]);
        bf16x8 pa1 = *(const bf16x8*)(&Pl[wv][(i * 16 + c) * 72 + ko + 32]);
#pragma unroll
        for (int j2 = 0; j2 < 2; ++j2) {
            o[i][j2] = __builtin_amdgcn_mfma_f32_16x16x32_bf16(pa0, vb[j2][0], o[i][j2], 0, 0, 0);
            o[i][j2] = __builtin_amdgcn_mfma_f32_16x16x32_bf16(pa1, vb[j2][1], o[i][j2], 0, 0, 0);
        }
    }
#pragma unroll
    for (int i = 0; i < 4; ++i)
#pragma unroll
        for (int r = 0; r < 4; ++r) {
            int row = i * 16 + g * 4 + r;
            if (row < LWIN) {
#pragma unroll
                for (int j2 = 0; j2 < 2; ++j2)
                    oattn[(size_t)(rowbase + row) * 256 + head * 32 + j2 * 16 + c]
                        = f2bu(o[i][j2][r]);
            }
        }
}

// ---------------- LN2 -> bf16, one wave per token -----------------------------
__global__ __launch_bounds__(256) void k_ln2(const float* __restrict__ x1,
        const float* __restrict__ g, const float* __restrict__ be,
        u16* __restrict__ h2) {
    int wave = threadIdx.x >> 6, lane = threadIdx.x & 63;
    int tok  = blockIdx.x * 4 + wave;
    const float* p = x1 + (size_t)tok * 256 + lane * 4;
    float4 v = *(const float4*)p;
    float s  = v.x + v.y + v.z + v.w;
    float sq = v.x * v.x + v.y * v.y + v.z * v.z + v.w * v.w;
    for (int o = 32; o; o >>= 1) { s += __shfl_xor(s, o); sq += __shfl_xor(sq, o); }
    float m  = s * (1.f / 256.f);
    float rs = rsqrtf(sq * (1.f / 256.f) - m * m + 1e-5f);
    float4 gv = *(const float4*)(g + lane * 4);
    float4 bv = *(const float4*)(be + lane * 4);
    unsigned p0 = (unsigned)f2bu((v.x - m) * rs * gv.x + bv.x)
                | ((unsigned)f2bu((v.y - m) * rs * gv.y + bv.y) << 16);
    unsigned p1 = (unsigned)f2bu((v.z - m) * rs * gv.z + bv.z)
                | ((unsigned)f2bu((v.w - m) * rs * gv.w + bv.w) << 16);
    unsigned* dst = (unsigned*)(h2 + (size_t)tok * 256 + lane * 4);
    dst[0] = p0; dst[1] = p1;
}

extern "C" void kernel_launch(void* const* d_in, const int* in_sizes, int n_in,
                              void* d_out, int out_size, void* d_ws, size_t ws_size,
                              hipStream_t stream) {
    const float* x      = (const float*)d_in[0];
    const float* ln1_g  = (const float*)d_in[1];
    const float* ln1_b  = (const float*)d_in[2];
    const float* ln2_g  = (const float*)d_in[3];
    const float* ln2_b  = (const float*)d_in[4];
    const float* qkv_w  = (const float*)d_in[5];
    const float* qkv_b  = (const float*)d_in[6];
    const float* proj_w = (const float*)d_in[7];
    const float* proj_b = (const float*)d_in[8];
    const float* ffn_w1 = (const float*)d_in[9];
    const float* ffn_b1 = (const float*)d_in[10];
    const float* ffn_w2 = (const float*)d_in[11];
    const float* ffn_b2 = (const float*)d_in[12];
    const float* lscale = (const float*)d_in[13];

    // workspace: total 104,333,312 B
    //   0        : wqt 768x256 bf16   (393,216)
    //   393216   : wpt 256x256 bf16   (131,072)
    //   524288   : w1t 1024x256 bf16  (524,288)
    //   1048576  : w2t 256x1024 bf16  (524,288)
    //   1572864  : P  25,690,112 B    hln -> o_attn -> h2 (bf16 50176x256)
    //   27262976 : Q  77,070,336 B    qkv bf16 (50176x768)
    //                                  then x1 fp32 (51,380,224) + f1c bf16 (25,690,112)
    char* wsb = (char*)d_ws;
    u16* wqt  = (u16*)(wsb);
    u16* wpt  = (u16*)(wsb + 393216);
    u16* w1t  = (u16*)(wsb + 524288);
    u16* w2t  = (u16*)(wsb + 1048576);
    u16* P    = (u16*)(wsb + 1572864);
    char* Qb  = wsb + 27262976;
    u16* qkvb = (u16*)Qb;
    float* x1 = (float*)Qb;
    u16* f1c  = (u16*)(Qb + 51380224);

    k_wconv<<<dim3(8, 24), 256, 0, stream>>>(qkv_w, wqt, 256, 768);
    k_wconv<<<dim3(8, 8),  256, 0, stream>>>(proj_w, wpt, 256, 256);
    k_wconv<<<dim3(8, 32), 256, 0, stream>>>(ffn_w1, w1t, 256, 1024);
    k_wconv<<<dim3(32, 8), 256, 0, stream>>>(ffn_w2, w2t, 1024, 256);

    k_ln1<<<16 * 98, 256, 0, stream>>>(x, ln1_g, ln1_b, P);
    k_mgemm<0><<<dim3(392, 6), 256, 0, stream>>>(P, wqt, qkv_b, qkvb, 256, 768,
                                                 nullptr, nullptr, 0);
    k_attn<<<2048, 256, 0, stream>>>(qkvb, P);
    k_mgemm<1><<<dim3(392, 2), 256, 0, stream>>>(P, wpt, proj_b, x1, 256, 256,
                                                 nullptr, nullptr, 0);
    k_addx<<<16 * 98, 256, 0, stream>>>(x, x1);
    k_ln2<<<12544, 256, 0, stream>>>(x1, ln2_g, ln2_b, P);
    for (int c = 0; c < 4; ++c) {
        k_mgemm<2><<<dim3(98, 8), 256, 0, stream>>>(P + (size_t)c * FCH * 256, w1t, ffn_b1,
                                                    f1c, 256, 1024, nullptr, nullptr, 0);
        k_mgemm<3><<<dim3(98, 2), 256, 0, stream>>>(f1c, w2t, ffn_b2, d_out, 1024, 256,
                                                    x1, lscale, c * FCH);
    }
}

// Round 6
// 310.675 us; speedup vs baseline: 5.2574x; 1.3147x over previous
//
#include <hip/hip_runtime.h>
#include <hip/hip_bf16.h>
#include <math.h>

typedef unsigned short u16;
typedef __bf16 bf16x8 __attribute__((ext_vector_type(8)));
typedef float  f32x4  __attribute__((ext_vector_type(4)));

#define DIMC 256
#define QSZ  56
#define WSZ  7
#define SSZ  3
#define LWIN 49
#define NWIN 64
#define HW   3136          // 56*56
#define NTOK 50176         // 16*3136
#define FFWD 1024
#define FCH  25088         // NTOK/2 ffn chunk rows

__device__ __forceinline__ u16 f2bu(float f) {
    __hip_bfloat16 h = __float2bfloat16(f);
    return __builtin_bit_cast(u16, h);
}
__device__ __forceinline__ float bu2f(u16 u) {
    unsigned v = (unsigned)u << 16;
    return __builtin_bit_cast(float, v);
}
__device__ __forceinline__ void gload_lds16(const void* g, void* l) {
    __builtin_amdgcn_global_load_lds((const __attribute__((address_space(1))) void*)g,
                                     (__attribute__((address_space(3))) void*)l, 16, 0, 0);
}

__device__ __forceinline__ int region_of(int h) {
    return (h < 49) ? 0 : ((h < 53) ? 1 : 2);
}

// partitioned row m = ((b*64 + wi)*49 + p) -> flat token index (with roll by -3)
__device__ __forceinline__ int row2tok(int m) {
    int b  = m / (NWIN * LWIN);
    int r  = m - b * (NWIN * LWIN);
    int wi = r / LWIN;
    int p  = r - wi * LWIN;
    int wh = wi >> 3, ww = wi & 7;
    int ph = p / 7,   pw = p - ph * 7;
    int hr = wh * 7 + ph, wr = ww * 7 + pw;
    int hs = hr + SSZ; if (hs >= QSZ) hs -= QSZ;
    int ws2 = wr + SSZ; if (ws2 >= QSZ) ws2 -= QSZ;
    return b * HW + hs * QSZ + ws2;
}

// ---------------- weight transpose + bf16 convert: Wt[n][k] = bf16(W[k][n]) ---
__global__ __launch_bounds__(256) void k_wconv(const float* __restrict__ W,
        u16* __restrict__ Wt, int K, int N) {
    __shared__ float tile[32][33];
    int k0 = blockIdx.x * 32, n0 = blockIdx.y * 32;
    int tx = threadIdx.x & 31, ty = threadIdx.x >> 5;
    for (int kk = ty; kk < 32; kk += 8)
        tile[kk][tx] = W[(size_t)(k0 + kk) * N + n0 + tx];
    __syncthreads();
    for (int nn = ty; nn < 32; nn += 8)
        Wt[(size_t)(n0 + nn) * K + k0 + tx] = f2bu(tile[tx][nn]);
}

// ---------------- K1: BCHW -> token-major transpose + LN1 -> bf16 -------------
__global__ __launch_bounds__(256) void k_ln1(const float* __restrict__ x,
        const float* __restrict__ g, const float* __restrict__ be,
        u16* __restrict__ hln) {
    __shared__ float tile[32][257];
    __shared__ float msh[32], rsh[32];
    int blk = blockIdx.x;            // 16 * 98
    int b   = blk / 98;
    int hw0 = (blk - b * 98) * 32;
    int t   = threadIdx.x;
    int tx  = t & 31, ty = t >> 5;
    for (int c = ty; c < 256; c += 8)
        tile[tx][c] = x[(size_t)(b * 256 + c) * HW + hw0 + tx];
    __syncthreads();
    int row = t >> 3, sub = t & 7;
    float s = 0.f, sq = 0.f;
    for (int c = sub * 32; c < sub * 32 + 32; ++c) {
        float v = tile[row][c]; s += v; sq += v * v;
    }
    for (int o = 4; o; o >>= 1) { s += __shfl_down(s, o, 8); sq += __shfl_down(sq, o, 8); }
    if (sub == 0) {
        float m   = s * (1.f / 256.f);
        float var = sq * (1.f / 256.f) - m * m;
        msh[row] = m; rsh[row] = rsqrtf(var + 1e-5f);
    }
    __syncthreads();
    float gg = g[t], bb = be[t];
    for (int r2 = 0; r2 < 32; ++r2) {
        float v = tile[r2][t];
        hln[(size_t)(b * HW + hw0 + r2) * 256 + t] = f2bu((v - msh[r2]) * rsh[r2] * gg + bb);
    }
}

// ---------------- MFMA bf16 GEMM, 128x128 tile, BK=32, 4 waves ----------------
// A [M][K] bf16 (MODE 0: rows gathered via row2tok), Bt [N][K] bf16.
// MODE 0: qkv  -> bf16 C = acc + bias                                  (N=768)
// MODE 1: proj -> bf16 x1 scattered (row2tok), = acc+bias+x_transposed (N=256)
// MODE 2: ffn1 -> bf16 relu(acc + bias)                                (N=1024)
// MODE 3: ffn2 -> fp32 BCHW d_out = x1(bf16) + ls*(acc+bias)           (N=256)
template<int MODE>
__global__ __launch_bounds__(256) void k_mgemm(
        const u16* __restrict__ A, const u16* __restrict__ Bt,
        const float* __restrict__ bias, void* __restrict__ Cv,
        int K, int N, const void* __restrict__ extra,
        const float* __restrict__ extra2, int grow0) {
    __shared__ __align__(16) u16 As[128 * 32];
    __shared__ __align__(16) u16 Bs[128 * 32];
    const int m0 = blockIdx.x * 128, n0 = blockIdx.y * 128;
    const int t = threadIdx.x, lane = t & 63;
    const int wv = t >> 6, wr = wv >> 1, wc = wv & 1;

    int ar0 = m0 + (t >> 2), ar1 = ar0 + 64;
    if (MODE == 0) { ar0 = row2tok(ar0); ar1 = row2tok(ar1); }
    const u16* gA0 = A  + (size_t)ar0 * K + (t & 3) * 8;
    const u16* gA1 = A  + (size_t)ar1 * K + (t & 3) * 8;
    const u16* gB0 = Bt + (size_t)(n0 + (t >> 2)) * K + (t & 3) * 8;
    const u16* gB1 = Bt + (size_t)(n0 + 64 + (t >> 2)) * K + (t & 3) * 8;
    u16* lA0 = As + t * 8;  u16* lA1 = As + 2048 + t * 8;
    u16* lB0 = Bs + t * 8;  u16* lB1 = Bs + 2048 + t * 8;

    f32x4 acc[4][4] = {};
    const int ra = wr * 64 + (lane & 15);
    const int rb = wc * 64 + (lane & 15);
    const int ko = (lane >> 4) * 8;

    for (int k0 = 0; k0 < K; k0 += 32) {
        __syncthreads();
        gload_lds16(gA0 + k0, lA0);
        gload_lds16(gA1 + k0, lA1);
        gload_lds16(gB0 + k0, lB0);
        gload_lds16(gB1 + k0, lB1);
        __syncthreads();
        bf16x8 af[4], bfr[4];
#pragma unroll
        for (int i = 0; i < 4; ++i)
            af[i] = *(const bf16x8*)(As + (ra + i * 16) * 32 + ko);
#pragma unroll
        for (int j = 0; j < 4; ++j)
            bfr[j] = *(const bf16x8*)(Bs + (rb + j * 16) * 32 + ko);
#pragma unroll
        for (int i = 0; i < 4; ++i)
#pragma unroll
            for (int j = 0; j < 4; ++j)
                acc[i][j] = __builtin_amdgcn_mfma_f32_16x16x32_bf16(af[i], bfr[j], acc[i][j], 0, 0, 0);
    }

    const int colb = n0 + wc * 64 + (lane & 15);       // + j*16
    const int rowb = m0 + wr * 64 + ((lane >> 4) * 4); // + i*16 + r

    if constexpr (MODE == 0) {
        u16* Cb = (u16*)Cv;
#pragma unroll
        for (int j = 0; j < 4; ++j) {
            int col = colb + j * 16; float bj = bias[col];
#pragma unroll
            for (int i = 0; i < 4; ++i) {
                int rw = rowb + i * 16;
#pragma unroll
                for (int r = 0; r < 4; ++r)
                    Cb[(size_t)(rw + r) * N + col] = f2bu(acc[i][j][r] + bj);
            }
        }
    } else if constexpr (MODE == 1) {
        u16* Cb = (u16*)Cv;                      // x1 bf16
        const float* xg = (const float*)extra;   // original x in BCHW
        int tok[4][4], bI[4][4], hw[4][4];
#pragma unroll
        for (int i = 0; i < 4; ++i)
#pragma unroll
            for (int r = 0; r < 4; ++r) {
                int tk = row2tok(rowb + i * 16 + r);
                tok[i][r] = tk; bI[i][r] = tk / HW; hw[i][r] = tk - (tk / HW) * HW;
            }
#pragma unroll
        for (int j = 0; j < 4; ++j) {
            int col = colb + j * 16; float bj = bias[col];
#pragma unroll
            for (int i = 0; i < 4; ++i)
#pragma unroll
                for (int r = 0; r < 4; ++r) {
                    float xv = xg[(size_t)(bI[i][r] * 256 + col) * HW + hw[i][r]];
                    Cb[(size_t)tok[i][r] * 256 + col] = f2bu(acc[i][j][r] + bj + xv);
                }
        }
    } else if constexpr (MODE == 2) {
        u16* Cb = (u16*)Cv;
#pragma unroll
        for (int j = 0; j < 4; ++j) {
            int col = colb + j * 16; float bj = bias[col];
#pragma unroll
            for (int i = 0; i < 4; ++i) {
                int rw = rowb + i * 16;
#pragma unroll
                for (int r = 0; r < 4; ++r)
                    Cb[(size_t)(rw + r) * N + col] = f2bu(fmaxf(acc[i][j][r] + bj, 0.f));
            }
        }
    } else {
        float* C = (float*)Cv;
        const u16* xr = (const u16*)extra;       // x1 bf16
#pragma unroll
        for (int j = 0; j < 4; ++j) {
            int col = colb + j * 16;
            float bj = bias[col], lj = extra2[col];
#pragma unroll
            for (int i = 0; i < 4; ++i) {
                int g  = grow0 + rowb + i * 16;   // g % 4 == 0, 3136 % 4 == 0:
                int b  = g / HW, hw = g - b * HW; // a 4-row pack never crosses batch
                f32x4 o;
#pragma unroll
                for (int r = 0; r < 4; ++r)
                    o[r] = bu2f(xr[(size_t)(g + r) * 256 + col]) + lj * (acc[i][j][r] + bj);
                *(f32x4*)(C + ((size_t)(b * 256 + col)) * HW + hw) = o;
            }
        }
    }
}

// ---------------- MFMA attention: one wave per (window, head) -----------------
// S = Q K^T (padded 64x64, K=32, 16 mfma), in-register masked softmax,
// P -> per-wave LDS (stride 72), V B-fragments built directly in registers
// from global (rows 49..63 zeroed: P tail cols are 0 but 0*Inf = NaN).
__global__ __launch_bounds__(256, 4) void k_attn(const u16* __restrict__ qkv,
        u16* __restrict__ oattn) {
    __shared__ __align__(16) u16 Pl[4][64 * 72];
    const int wv = threadIdx.x >> 6, lane = threadIdx.x & 63;
    const int task = blockIdx.x * 4 + wv;    // 8192 = 1024 win * 8 heads
    const int head = task & 7, win = task >> 3, wi = win & 63;
    const int rowbase = win * LWIN;
    const int g = lane >> 4, c = lane & 15, ko = g * 8;
    const u16* qb = qkv + (size_t)rowbase * 768 + head * 32;

    // --- S = Q K^T ---
    bf16x8 qf[4], kf[4];
#pragma unroll
    for (int i = 0; i < 4; ++i) {
        int r0 = i * 16 + c; if (r0 > 48) r0 = 48;   // clamp: garbage rows unused
        qf[i] = *(const bf16x8*)(qb + (size_t)r0 * 768 + ko);
        kf[i] = *(const bf16x8*)(qb + (size_t)r0 * 768 + 256 + ko);
    }
    f32x4 s[4][4] = {};
#pragma unroll
    for (int i = 0; i < 4; ++i)
#pragma unroll
        for (int j = 0; j < 4; ++j)
            s[i][j] = __builtin_amdgcn_mfma_f32_16x16x32_bf16(qf[i], kf[j], s[i][j], 0, 0, 0);

    // --- V B-fragments direct to registers (k >= 49 zeroed) ---
    bf16x8 vb[2][2];
#pragma unroll
    for (int j2 = 0; j2 < 2; ++j2) {
        int d = j2 * 16 + c;
#pragma unroll
        for (int h = 0; h < 2; ++h)
#pragma unroll
            for (int tt = 0; tt < 8; ++tt) {
                int k = h * 32 + ko + tt;
                u16 val = (k < LWIN) ? qb[(size_t)k * 768 + 512 + d] : (u16)0;
                vb[j2][h][tt] = __builtin_bit_cast(__bf16, val);
            }
    }

    // --- masked softmax in C-layout (row = i*16+g*4+r, col = j*16+c) ---
    const int wh7 = (wi >> 3) * 7, ww7 = (wi & 7) * 7;
    int idj[4]; bool jok[4];
#pragma unroll
    for (int j = 0; j < 4; ++j) {
        int col = j * 16 + c;
        jok[j] = col < LWIN;
        int p = jok[j] ? col : 48;
        idj[j] = region_of(wh7 + p / 7) * 3 + region_of(ww7 + p % 7);
    }
#pragma unroll
    for (int i = 0; i < 4; ++i) {
#pragma unroll
        for (int r = 0; r < 4; ++r) {
            int row = i * 16 + g * 4 + r;
            int p = row < LWIN ? row : 48;
            int idi = region_of(wh7 + p / 7) * 3 + region_of(ww7 + p % 7);
            float mx = -1e30f;
#pragma unroll
            for (int j = 0; j < 4; ++j) {
                float tv = jok[j] ? fmaf(s[i][j][r], 0.17677669529663687f,
                                         (idi == idj[j]) ? 0.f : -100.f)
                                  : -1e30f;
                s[i][j][r] = tv;
                mx = fmaxf(mx, tv);
            }
            for (int o = 8; o; o >>= 1) mx = fmaxf(mx, __shfl_xor(mx, o));
            float ps = 0.f;
#pragma unroll
            for (int j = 0; j < 4; ++j) {
                float e = __expf(s[i][j][r] - mx);
                s[i][j][r] = e; ps += e;
            }
            for (int o = 8; o; o >>= 1) ps += __shfl_xor(ps, o);
            float inv = 1.f / ps;
#pragma unroll
            for (int j = 0; j < 4; ++j)
                Pl[wv][row * 72 + j * 16 + c] = f2bu(s[i][j][r] * inv);
        }
    }
    // per-wave LDS: no block barrier needed (compiler inserts lgkmcnt waits)

    // --- O = P V (M=64, N=32, K=64) ---
    f32x4 o[4][2] = {};
#pragma unroll
    for (int i = 0; i < 4; ++i) {
        bf16x8 pa0 = *(const bf16x8*)(&Pl[wv][(i * 16 + c) * 72 + ko]);
        bf16x8 pa1 = *(const bf16x8*)(&Pl[wv][(i * 16 + c) * 72 + ko + 32]);
#pragma unroll
        for (int j2 = 0; j2 < 2; ++j2) {
            o[i][j2] = __builtin_amdgcn_mfma_f32_16x16x32_bf16(pa0, vb[j2][0], o[i][j2], 0, 0, 0);
            o[i][j2] = __builtin_amdgcn_mfma_f32_16x16x32_bf16(pa1, vb[j2][1], o[i][j2], 0, 0, 0);
        }
    }
#pragma unroll
    for (int i = 0; i < 4; ++i)
#pragma unroll
        for (int r = 0; r < 4; ++r) {
            int row = i * 16 + g * 4 + r;
            if (row < LWIN) {
#pragma unroll
                for (int j2 = 0; j2 < 2; ++j2)
                    oattn[(size_t)(rowbase + row) * 256 + head * 32 + j2 * 16 + c]
                        = f2bu(o[i][j2][r]);
            }
        }
}

// ---------------- LN2 (bf16 in) -> bf16, one wave per token -------------------
__global__ __launch_bounds__(256) void k_ln2(const u16* __restrict__ x1,
        const float* __restrict__ g, const float* __restrict__ be,
        u16* __restrict__ h2) {
    int wave = threadIdx.x >> 6, lane = threadIdx.x & 63;
    int tok  = blockIdx.x * 4 + wave;
    const u16* p = x1 + (size_t)tok * 256 + lane * 4;
    ushort4 v4 = *(const ushort4*)p;
    float vx = bu2f(v4.x), vy = bu2f(v4.y), vz = bu2f(v4.z), vw = bu2f(v4.w);
    float s  = vx + vy + vz + vw;
    float sq = vx * vx + vy * vy + vz * vz + vw * vw;
    for (int o = 32; o; o >>= 1) { s += __shfl_xor(s, o); sq += __shfl_xor(sq, o); }
    float m  = s * (1.f / 256.f);
    float rs = rsqrtf(sq * (1.f / 256.f) - m * m + 1e-5f);
    float4 gv = *(const float4*)(g + lane * 4);
    float4 bv = *(const float4*)(be + lane * 4);
    unsigned p0 = (unsigned)f2bu((vx - m) * rs * gv.x + bv.x)
                | ((unsigned)f2bu((vy - m) * rs * gv.y + bv.y) << 16);
    unsigned p1 = (unsigned)f2bu((vz - m) * rs * gv.z + bv.z)
                | ((unsigned)f2bu((vw - m) * rs * gv.w + bv.w) << 16);
    unsigned* dst = (unsigned*)(h2 + (size_t)tok * 256 + lane * 4);
    dst[0] = p0; dst[1] = p1;
}

extern "C" void kernel_launch(void* const* d_in, const int* in_sizes, int n_in,
                              void* d_out, int out_size, void* d_ws, size_t ws_size,
                              hipStream_t stream) {
    const float* x      = (const float*)d_in[0];
    const float* ln1_g  = (const float*)d_in[1];
    const float* ln1_b  = (const float*)d_in[2];
    const float* ln2_g  = (const float*)d_in[3];
    const float* ln2_b  = (const float*)d_in[4];
    const float* qkv_w  = (const float*)d_in[5];
    const float* qkv_b  = (const float*)d_in[6];
    const float* proj_w = (const float*)d_in[7];
    const float* proj_b = (const float*)d_in[8];
    const float* ffn_w1 = (const float*)d_in[9];
    const float* ffn_b1 = (const float*)d_in[10];
    const float* ffn_w2 = (const float*)d_in[11];
    const float* ffn_b2 = (const float*)d_in[12];
    const float* lscale = (const float*)d_in[13];

    // workspace: total 104,333,312 B
    //   0        : wqt 768x256 bf16   (393,216)
    //   393216   : wpt 256x256 bf16   (131,072)
    //   524288   : w1t 1024x256 bf16  (524,288)
    //   1048576  : w2t 256x1024 bf16  (524,288)
    //   1572864  : P  25,690,112 B    hln -> o_attn -> h2 (bf16 50176x256)
    //   27262976 : Q  77,070,336 B    phase1: qkv bf16 (50176x768)
    //                                 phase2: x1 bf16 (25,690,112)
    //                                        + f1c bf16 (51,380,224) @ +25,690,112
    char* wsb = (char*)d_ws;
    u16* wqt  = (u16*)(wsb);
    u16* wpt  = (u16*)(wsb + 393216);
    u16* w1t  = (u16*)(wsb + 524288);
    u16* w2t  = (u16*)(wsb + 1048576);
    u16* P    = (u16*)(wsb + 1572864);
    char* Qb  = wsb + 27262976;
    u16* qkvb = (u16*)Qb;
    u16* x1b  = (u16*)Qb;
    u16* f1c  = (u16*)(Qb + 25690112);

    k_wconv<<<dim3(8, 24), 256, 0, stream>>>(qkv_w, wqt, 256, 768);
    k_wconv<<<dim3(8, 8),  256, 0, stream>>>(proj_w, wpt, 256, 256);
    k_wconv<<<dim3(8, 32), 256, 0, stream>>>(ffn_w1, w1t, 256, 1024);
    k_wconv<<<dim3(32, 8), 256, 0, stream>>>(ffn_w2, w2t, 1024, 256);

    k_ln1<<<16 * 98, 256, 0, stream>>>(x, ln1_g, ln1_b, P);
    k_mgemm<0><<<dim3(392, 6), 256, 0, stream>>>(P, wqt, qkv_b, qkvb, 256, 768,
                                                 nullptr, nullptr, 0);
    k_attn<<<2048, 256, 0, stream>>>(qkvb, P);
    // proj + reverse-partition scatter + fused x-transpose residual -> x1 bf16
    k_mgemm<1><<<dim3(392, 2), 256, 0, stream>>>(P, wpt, proj_b, x1b, 256, 256,
                                                 x, nullptr, 0);
    k_ln2<<<12544, 256, 0, stream>>>(x1b, ln2_g, ln2_b, P);
    for (int c = 0; c < 2; ++c) {
        k_mgemm<2><<<dim3(196, 8), 256, 0, stream>>>(P + (size_t)c * FCH * 256, w1t, ffn_b1,
                                                     f1c, 256, 1024, nullptr, nullptr, 0);
        k_mgemm<3><<<dim3(196, 2), 256, 0, stream>>>(f1c, w2t, ffn_b2, d_out, 1024, 256,
                                                     x1b, lscale, c * FCH);
    }
}

// Round 7
// 286.995 us; speedup vs baseline: 5.6912x; 1.0825x over previous
//
#include <hip/hip_runtime.h>
#include <hip/hip_bf16.h>
#include <math.h>

typedef unsigned short u16;
typedef __bf16 bf16x8 __attribute__((ext_vector_type(8)));
typedef float  f32x4  __attribute__((ext_vector_type(4)));

#define DIMC 256
#define QSZ  56
#define WSZ  7
#define SSZ  3
#define LWIN 49
#define NWIN 64
#define HW   3136          // 56*56
#define NTOK 50176         // 16*3136
#define FFWD 1024
#define FCH  25088         // NTOK/2 ffn chunk rows

__device__ __forceinline__ u16 f2bu(float f) {
    __hip_bfloat16 h = __float2bfloat16(f);
    return __builtin_bit_cast(u16, h);
}
__device__ __forceinline__ float bu2f(u16 u) {
    unsigned v = (unsigned)u << 16;
    return __builtin_bit_cast(float, v);
}
__device__ __forceinline__ void gload_lds16(const void* g, void* l) {
    __builtin_amdgcn_global_load_lds((const __attribute__((address_space(1))) void*)g,
                                     (__attribute__((address_space(3))) void*)l, 16, 0, 0);
}

__device__ __forceinline__ int region_of(int h) {
    return (h < 49) ? 0 : ((h < 53) ? 1 : 2);
}

// partitioned row m = ((b*64 + wi)*49 + p) -> flat token index (with roll by -3)
__device__ __forceinline__ int row2tok(int m) {
    int b  = m / (NWIN * LWIN);
    int r  = m - b * (NWIN * LWIN);
    int wi = r / LWIN;
    int p  = r - wi * LWIN;
    int wh = wi >> 3, ww = wi & 7;
    int ph = p / 7,   pw = p - ph * 7;
    int hr = wh * 7 + ph, wr = ww * 7 + pw;
    int hs = hr + SSZ; if (hs >= QSZ) hs -= QSZ;
    int ws2 = wr + SSZ; if (ws2 >= QSZ) ws2 -= QSZ;
    return b * HW + hs * QSZ + ws2;
}

// ---------------- weight transpose + bf16 convert: Wt[n][k] = bf16(W[k][n]) ---
__global__ __launch_bounds__(256) void k_wconv(const float* __restrict__ W,
        u16* __restrict__ Wt, int K, int N) {
    __shared__ float tile[32][33];
    int k0 = blockIdx.x * 32, n0 = blockIdx.y * 32;
    int tx = threadIdx.x & 31, ty = threadIdx.x >> 5;
    for (int kk = ty; kk < 32; kk += 8)
        tile[kk][tx] = W[(size_t)(k0 + kk) * N + n0 + tx];
    __syncthreads();
    for (int nn = ty; nn < 32; nn += 8)
        Wt[(size_t)(n0 + nn) * K + k0 + tx] = f2bu(tile[tx][nn]);
}

// ---------------- K1: BCHW -> token-major transpose + LN1 -> bf16 -------------
__global__ __launch_bounds__(256) void k_ln1(const float* __restrict__ x,
        const float* __restrict__ g, const float* __restrict__ be,
        u16* __restrict__ hln) {
    __shared__ float tile[32][257];
    __shared__ float msh[32], rsh[32];
    int blk = blockIdx.x;            // 16 * 98
    int b   = blk / 98;
    int hw0 = (blk - b * 98) * 32;
    int t   = threadIdx.x;
    int tx  = t & 31, ty = t >> 5;
    for (int c = ty; c < 256; c += 8)
        tile[tx][c] = x[(size_t)(b * 256 + c) * HW + hw0 + tx];
    __syncthreads();
    int row = t >> 3, sub = t & 7;
    float s = 0.f, sq = 0.f;
    for (int c = sub * 32; c < sub * 32 + 32; ++c) {
        float v = tile[row][c]; s += v; sq += v * v;
    }
    for (int o = 4; o; o >>= 1) { s += __shfl_down(s, o, 8); sq += __shfl_down(sq, o, 8); }
    if (sub == 0) {
        float m   = s * (1.f / 256.f);
        float var = sq * (1.f / 256.f) - m * m;
        msh[row] = m; rsh[row] = rsqrtf(var + 1e-5f);
    }
    __syncthreads();
    float gg = g[t], bb = be[t];
    for (int r2 = 0; r2 < 32; ++r2) {
        float v = tile[r2][t];
        hln[(size_t)(b * HW + hw0 + r2) * 256 + t] = f2bu((v - msh[r2]) * rsh[r2] * gg + bb);
    }
}

// ---------------- LN2 + residual: x1 = proj_out + transpose(x); h2 = LN(x1) ---
// po/x1b is IN-PLACE: holds proj_out (token-major bf16) on entry, x1 on exit.
__global__ __launch_bounds__(256) void k_ln2t(const float* __restrict__ x,
        u16* __restrict__ x1b, const float* __restrict__ g,
        const float* __restrict__ be, u16* __restrict__ h2) {
    __shared__ float tile[32][257];
    __shared__ float msh[32], rsh[32];
    int blk = blockIdx.x;            // 16 * 98
    int b   = blk / 98;
    int hw0 = (blk - b * 98) * 32;
    int t   = threadIdx.x;
    int tx  = t & 31, ty = t >> 5;
    for (int c = ty; c < 256; c += 8)
        tile[tx][c] = x[(size_t)(b * 256 + c) * HW + hw0 + tx];
    __syncthreads();
    size_t base = (size_t)b * HW + hw0;
    for (int r2 = 0; r2 < 32; ++r2) {
        float v = tile[r2][t] + bu2f(x1b[(base + r2) * 256 + t]);
        tile[r2][t] = v;
        x1b[(base + r2) * 256 + t] = f2bu(v);
    }
    __syncthreads();
    int row = t >> 3, sub = t & 7;
    float s = 0.f, sq = 0.f;
    for (int c = sub * 32; c < sub * 32 + 32; ++c) {
        float v = tile[row][c]; s += v; sq += v * v;
    }
    for (int o = 4; o; o >>= 1) { s += __shfl_down(s, o, 8); sq += __shfl_down(sq, o, 8); }
    if (sub == 0) {
        float m   = s * (1.f / 256.f);
        float var = sq * (1.f / 256.f) - m * m;
        msh[row] = m; rsh[row] = rsqrtf(var + 1e-5f);
    }
    __syncthreads();
    float gg = g[t], bb = be[t];
    for (int r2 = 0; r2 < 32; ++r2) {
        float v = tile[r2][t];
        h2[(base + r2) * 256 + t] = f2bu((v - msh[r2]) * rsh[r2] * gg + bb);
    }
}

// ---------------- MFMA bf16 GEMM, 128x128 tile, BK=32, 4 waves ----------------
// A [M][K] bf16 (MODE 0: rows gathered via row2tok), Bt [N][K] bf16.
// MODE 0: qkv  -> bf16 C = acc + bias                          (N=768)
// MODE 1: proj -> bf16 proj_out scattered rows (row2tok)+bias  (N=256)
// MODE 2: ffn1 -> bf16 relu(acc + bias)                        (N=1024)
// MODE 3: ffn2 -> fp32 BCHW d_out = x1(bf16) + ls*(acc+bias)   (N=256)
template<int MODE>
__global__ __launch_bounds__(256) void k_mgemm(
        const u16* __restrict__ A, const u16* __restrict__ Bt,
        const float* __restrict__ bias, void* __restrict__ Cv,
        int K, int N, const void* __restrict__ extra,
        const float* __restrict__ extra2, int grow0) {
    __shared__ __align__(16) u16 As[128 * 32];
    __shared__ __align__(16) u16 Bs[128 * 32];
    const int m0 = blockIdx.x * 128, n0 = blockIdx.y * 128;
    const int t = threadIdx.x, lane = t & 63;
    const int wv = t >> 6, wr = wv >> 1, wc = wv & 1;

    int ar0 = m0 + (t >> 2), ar1 = ar0 + 64;
    if (MODE == 0) { ar0 = row2tok(ar0); ar1 = row2tok(ar1); }
    const u16* gA0 = A  + (size_t)ar0 * K + (t & 3) * 8;
    const u16* gA1 = A  + (size_t)ar1 * K + (t & 3) * 8;
    const u16* gB0 = Bt + (size_t)(n0 + (t >> 2)) * K + (t & 3) * 8;
    const u16* gB1 = Bt + (size_t)(n0 + 64 + (t >> 2)) * K + (t & 3) * 8;
    u16* lA0 = As + t * 8;  u16* lA1 = As + 2048 + t * 8;
    u16* lB0 = Bs + t * 8;  u16* lB1 = Bs + 2048 + t * 8;

    f32x4 acc[4][4] = {};
    const int ra = wr * 64 + (lane & 15);
    const int rb = wc * 64 + (lane & 15);
    const int ko = (lane >> 4) * 8;

    for (int k0 = 0; k0 < K; k0 += 32) {
        __syncthreads();
        gload_lds16(gA0 + k0, lA0);
        gload_lds16(gA1 + k0, lA1);
        gload_lds16(gB0 + k0, lB0);
        gload_lds16(gB1 + k0, lB1);
        __syncthreads();
        bf16x8 af[4], bfr[4];
#pragma unroll
        for (int i = 0; i < 4; ++i)
            af[i] = *(const bf16x8*)(As + (ra + i * 16) * 32 + ko);
#pragma unroll
        for (int j = 0; j < 4; ++j)
            bfr[j] = *(const bf16x8*)(Bs + (rb + j * 16) * 32 + ko);
#pragma unroll
        for (int i = 0; i < 4; ++i)
#pragma unroll
            for (int j = 0; j < 4; ++j)
                acc[i][j] = __builtin_amdgcn_mfma_f32_16x16x32_bf16(af[i], bfr[j], acc[i][j], 0, 0, 0);
    }

    const int colb = n0 + wc * 64 + (lane & 15);       // + j*16
    const int rowb = m0 + wr * 64 + ((lane >> 4) * 4); // + i*16 + r

    if constexpr (MODE == 0) {
        u16* Cb = (u16*)Cv;
#pragma unroll
        for (int j = 0; j < 4; ++j) {
            int col = colb + j * 16; float bj = bias[col];
#pragma unroll
            for (int i = 0; i < 4; ++i) {
                int rw = rowb + i * 16;
#pragma unroll
                for (int r = 0; r < 4; ++r)
                    Cb[(size_t)(rw + r) * N + col] = f2bu(acc[i][j][r] + bj);
            }
        }
    } else if constexpr (MODE == 1) {
        u16* Cb = (u16*)Cv;                      // proj_out token-scattered
        int tok[4][4];
#pragma unroll
        for (int i = 0; i < 4; ++i)
#pragma unroll
            for (int r = 0; r < 4; ++r)
                tok[i][r] = row2tok(rowb + i * 16 + r);
#pragma unroll
        for (int j = 0; j < 4; ++j) {
            int col = colb + j * 16; float bj = bias[col];
#pragma unroll
            for (int i = 0; i < 4; ++i)
#pragma unroll
                for (int r = 0; r < 4; ++r)
                    Cb[(size_t)tok[i][r] * 256 + col] = f2bu(acc[i][j][r] + bj);
        }
    } else if constexpr (MODE == 2) {
        u16* Cb = (u16*)Cv;
#pragma unroll
        for (int j = 0; j < 4; ++j) {
            int col = colb + j * 16; float bj = bias[col];
#pragma unroll
            for (int i = 0; i < 4; ++i) {
                int rw = rowb + i * 16;
#pragma unroll
                for (int r = 0; r < 4; ++r)
                    Cb[(size_t)(rw + r) * N + col] = f2bu(fmaxf(acc[i][j][r] + bj, 0.f));
            }
        }
    } else {
        float* C = (float*)Cv;
        const u16* xr = (const u16*)extra;       // x1 bf16
#pragma unroll
        for (int j = 0; j < 4; ++j) {
            int col = colb + j * 16;
            float bj = bias[col], lj = extra2[col];
#pragma unroll
            for (int i = 0; i < 4; ++i) {
                int g  = grow0 + rowb + i * 16;   // g % 4 == 0, 3136 % 4 == 0:
                int b  = g / HW, hw = g - b * HW; // a 4-row pack never crosses batch
                f32x4 o;
#pragma unroll
                for (int r = 0; r < 4; ++r)
                    o[r] = bu2f(xr[(size_t)(g + r) * 256 + col]) + lj * (acc[i][j][r] + bj);
                *(f32x4*)(C + ((size_t)(b * 256 + col)) * HW + hw) = o;
            }
        }
    }
}

// ---------------- MFMA attention: one wave per (window, head) -----------------
// S = Q K^T (padded 64x64, K=32, 16 mfma), in-register masked softmax,
// P -> per-wave LDS (stride 72), V B-fragments built directly in registers
// from global (rows 49..63 zeroed: P tail cols are 0 but 0*Inf = NaN).
__global__ __launch_bounds__(256, 4) void k_attn(const u16* __restrict__ qkv,
        u16* __restrict__ oattn) {
    __shared__ __align__(16) u16 Pl[4][64 * 72];
    const int wv = threadIdx.x >> 6, lane = threadIdx.x & 63;
    const int task = blockIdx.x * 4 + wv;    // 8192 = 1024 win * 8 heads
    const int head = task & 7, win = task >> 3, wi = win & 63;
    const int rowbase = win * LWIN;
    const int g = lane >> 4, c = lane & 15, ko = g * 8;
    const u16* qb = qkv + (size_t)rowbase * 768 + head * 32;

    // --- S = Q K^T ---
    bf16x8 qf[4], kf[4];
#pragma unroll
    for (int i = 0; i < 4; ++i) {
        int r0 = i * 16 + c; if (r0 > 48) r0 = 48;   // clamp: garbage rows unused
        qf[i] = *(const bf16x8*)(qb + (size_t)r0 * 768 + ko);
        kf[i] = *(const bf16x8*)(qb + (size_t)r0 * 768 + 256 + ko);
    }
    f32x4 s[4][4] = {};
#pragma unroll
    for (int i = 0; i < 4; ++i)
#pragma unroll
        for (int j = 0; j < 4; ++j)
            s[i][j] = __builtin_amdgcn_mfma_f32_16x16x32_bf16(qf[i], kf[j], s[i][j], 0, 0, 0);

    // --- V B-fragments direct to registers (k >= 49 zeroed) ---
    bf16x8 vb[2][2];
#pragma unroll
    for (int j2 = 0; j2 < 2; ++j2) {
        int d = j2 * 16 + c;
#pragma unroll
        for (int h = 0; h < 2; ++h)
#pragma unroll
            for (int tt = 0; tt < 8; ++tt) {
                int k = h * 32 + ko + tt;
                u16 val = (k < LWIN) ? qb[(size_t)k * 768 + 512 + d] : (u16)0;
                vb[j2][h][tt] = __builtin_bit_cast(__bf16, val);
            }
    }

    // --- masked softmax in C-layout (row = i*16+g*4+r, col = j*16+c) ---
    const int wh7 = (wi >> 3) * 7, ww7 = (wi & 7) * 7;
    int idj[4]; bool jok[4];
#pragma unroll
    for (int j = 0; j < 4; ++j) {
        int col = j * 16 + c;
        jok[j] = col < LWIN;
        int p = jok[j] ? col : 48;
        idj[j] = region_of(wh7 + p / 7) * 3 + region_of(ww7 + p % 7);
    }
#pragma unroll
    for (int i = 0; i < 4; ++i) {
#pragma unroll
        for (int r = 0; r < 4; ++r) {
            int row = i * 16 + g * 4 + r;
            int p = row < LWIN ? row : 48;
            int idi = region_of(wh7 + p / 7) * 3 + region_of(ww7 + p % 7);
            float mx = -1e30f;
#pragma unroll
            for (int j = 0; j < 4; ++j) {
                float tv = jok[j] ? fmaf(s[i][j][r], 0.17677669529663687f,
                                         (idi == idj[j]) ? 0.f : -100.f)
                                  : -1e30f;
                s[i][j][r] = tv;
                mx = fmaxf(mx, tv);
            }
            for (int o = 8; o; o >>= 1) mx = fmaxf(mx, __shfl_xor(mx, o));
            float ps = 0.f;
#pragma unroll
            for (int j = 0; j < 4; ++j) {
                float e = __expf(s[i][j][r] - mx);
                s[i][j][r] = e; ps += e;
            }
            for (int o = 8; o; o >>= 1) ps += __shfl_xor(ps, o);
            float inv = 1.f / ps;
#pragma unroll
            for (int j = 0; j < 4; ++j)
                Pl[wv][row * 72 + j * 16 + c] = f2bu(s[i][j][r] * inv);
        }
    }
    // per-wave LDS: no block barrier needed (compiler inserts lgkmcnt waits)

    // --- O = P V (M=64, N=32, K=64) ---
    f32x4 o[4][2] = {};
#pragma unroll
    for (int i = 0; i < 4; ++i) {
        bf16x8 pa0 = *(const bf16x8*)(&Pl[wv][(i * 16 + c) * 72 + ko]);
        bf16x8 pa1 = *(const bf16x8*)(&Pl[wv][(i * 16 + c) * 72 + ko + 32]);
#pragma unroll
        for (int j2 = 0; j2 < 2; ++j2) {
            o[i][j2] = __builtin_amdgcn_mfma_f32_16x16x32_bf16(pa0, vb[j2][0], o[i][j2], 0, 0, 0);
            o[i][j2] = __builtin_amdgcn_mfma_f32_16x16x32_bf16(pa1, vb[j2][1], o[i][j2], 0, 0, 0);
        }
    }
#pragma unroll
    for (int i = 0; i < 4; ++i)
#pragma unroll
        for (int r = 0; r < 4; ++r) {
            int row = i * 16 + g * 4 + r;
            if (row < LWIN) {
#pragma unroll
                for (int j2 = 0; j2 < 2; ++j2)
                    oattn[(size_t)(rowbase + row) * 256 + head * 32 + j2 * 16 + c]
                        = f2bu(o[i][j2][r]);
            }
        }
}

extern "C" void kernel_launch(void* const* d_in, const int* in_sizes, int n_in,
                              void* d_out, int out_size, void* d_ws, size_t ws_size,
                              hipStream_t stream) {
    const float* x      = (const float*)d_in[0];
    const float* ln1_g  = (const float*)d_in[1];
    const float* ln1_b  = (const float*)d_in[2];
    const float* ln2_g  = (const float*)d_in[3];
    const float* ln2_b  = (const float*)d_in[4];
    const float* qkv_w  = (const float*)d_in[5];
    const float* qkv_b  = (const float*)d_in[6];
    const float* proj_w = (const float*)d_in[7];
    const float* proj_b = (const float*)d_in[8];
    const float* ffn_w1 = (const float*)d_in[9];
    const float* ffn_b1 = (const float*)d_in[10];
    const float* ffn_w2 = (const float*)d_in[11];
    const float* ffn_b2 = (const float*)d_in[12];
    const float* lscale = (const float*)d_in[13];

    // workspace: total 104,333,312 B
    //   0        : wqt 768x256 bf16   (393,216)
    //   393216   : wpt 256x256 bf16   (131,072)
    //   524288   : w1t 1024x256 bf16  (524,288)
    //   1048576  : w2t 256x1024 bf16  (524,288)
    //   1572864  : P  25,690,112 B    hln -> o_attn -> h2 (bf16 50176x256)
    //   27262976 : Q  77,070,336 B    phase1: qkv bf16 (50176x768)
    //                                 phase2: proj_out->x1 bf16 (25,690,112)
    //                                        + f1c bf16 (51,380,224) @ +25,690,112
    char* wsb = (char*)d_ws;
    u16* wqt  = (u16*)(wsb);
    u16* wpt  = (u16*)(wsb + 393216);
    u16* w1t  = (u16*)(wsb + 524288);
    u16* w2t  = (u16*)(wsb + 1048576);
    u16* P    = (u16*)(wsb + 1572864);
    char* Qb  = wsb + 27262976;
    u16* qkvb = (u16*)Qb;
    u16* x1b  = (u16*)Qb;
    u16* f1c  = (u16*)(Qb + 25690112);

    k_wconv<<<dim3(8, 24), 256, 0, stream>>>(qkv_w, wqt, 256, 768);
    k_wconv<<<dim3(8, 8),  256, 0, stream>>>(proj_w, wpt, 256, 256);
    k_wconv<<<dim3(8, 32), 256, 0, stream>>>(ffn_w1, w1t, 256, 1024);
    k_wconv<<<dim3(32, 8), 256, 0, stream>>>(ffn_w2, w2t, 1024, 256);

    k_ln1<<<16 * 98, 256, 0, stream>>>(x, ln1_g, ln1_b, P);
    k_mgemm<0><<<dim3(392, 6), 256, 0, stream>>>(P, wqt, qkv_b, qkvb, 256, 768,
                                                 nullptr, nullptr, 0);
    k_attn<<<2048, 256, 0, stream>>>(qkvb, P);
    // proj + reverse-partition scatter -> proj_out (token-major bf16)
    k_mgemm<1><<<dim3(392, 2), 256, 0, stream>>>(P, wpt, proj_b, x1b, 256, 256,
                                                 nullptr, nullptr, 0);
    // x1 = proj_out + transpose(x) (in-place), h2 = LN2(x1) -> P
    k_ln2t<<<16 * 98, 256, 0, stream>>>(x, x1b, ln2_g, ln2_b, P);
    for (int c = 0; c < 2; ++c) {
        k_mgemm<2><<<dim3(196, 8), 256, 0, stream>>>(P + (size_t)c * FCH * 256, w1t, ffn_b1,
                                                     f1c, 256, 1024, nullptr, nullptr, 0);
        k_mgemm<3><<<dim3(196, 2), 256, 0, stream>>>(f1c, w2t, ffn_b2, d_out, 1024, 256,
                                                     x1b, lscale, c * FCH);
    }
}